// Round 1
// baseline (750.326 us; speedup 1.0000x reference)
//
#include <hip/hip_runtime.h>
#include <hip/hip_bf16.h>

#define NN 16384
#define KNN 10
#define HD 128
#define NL 7
#define TM 8
#define EDG 80   // TM*KNN

// per-layer bf16 weight layout offsets (in elements)
#define W1E_OFF 0        // [128][160]  (k 0..127 = hh_src rows 1..128, k128 = radial row 0, k129..159 = 0)
#define W1D_OFF 20480    // [128][128]  (hh_dst rows 129..256)
#define W2_OFF  36864    // [128][128]
#define C1_OFF  53248    // [128][128]
#define N1_OFF  69632    // [128][256]
#define N2_OFF  102400   // [128][128]
#define WL_STRIDE 118784 // elems per layer

typedef float fv4 __attribute__((ext_vector_type(4)));
typedef short bv8 __attribute__((ext_vector_type(8)));

static __device__ __forceinline__ unsigned short f2b(float f) {
  __hip_bfloat16 h = __float2bfloat16(f);
  return __builtin_bit_cast(unsigned short, h);
}
static __device__ __forceinline__ float b2f(unsigned short u) {
  unsigned int x = ((unsigned int)u) << 16;
  return __builtin_bit_cast(float, x);
}
static __device__ __forceinline__ float silu_f(float x) {
  return x / (1.0f + __expf(-x));
}
#define MFMA(a,b,c) __builtin_amdgcn_mfma_f32_16x16x32_bf16((a),(b),(c),0,0,0)

// ---------------- weight prep: fp32 -> bf16 transposed layouts ----------------
__global__ void prep_kernel(const float* __restrict__ ew1, const float* __restrict__ ew2,
                            const float* __restrict__ cw1, const float* __restrict__ nw1,
                            const float* __restrict__ nw2, unsigned short* __restrict__ wt)
{
  int g = blockIdx.x * 256 + threadIdx.x;
  if (g >= NL * WL_STRIDE) return;
  int l = g / WL_STRIDE;
  int r = g % WL_STRIDE;
  float v;
  if (r < 20480) {                       // W1eT [c][k], k padded to 160
    int c = r / 160, k = r % 160;
    if (k < 128)      v = ew1[(l*257 + 1 + k)*128 + c];
    else if (k == 128) v = ew1[(l*257)*128 + c];
    else               v = 0.f;
  } else if (r < 36864) {                // W1dT
    int q = r - 20480; int c = q >> 7, k = q & 127;
    v = ew1[(l*257 + 129 + k)*128 + c];
  } else if (r < 53248) {                // W2T
    int q = r - 36864; int c = q >> 7, k = q & 127;
    v = ew2[(l*128 + k)*128 + c];
  } else if (r < 69632) {                // C1T
    int q = r - 53248; int c = q >> 7, k = q & 127;
    v = cw1[(l*128 + k)*128 + c];
  } else if (r < 102400) {               // N1T [c][k0..255]
    int q = r - 69632; int c = q >> 8, k = q & 255;
    v = nw1[(l*256 + k)*128 + c];
  } else {                               // N2T
    int q = r - 102400; int c = q >> 7, k = q & 127;
    v = nw2[(l*128 + k)*128 + c];
  }
  wt[g] = f2b(v);
}

// ---------------- embedding_in + x init ----------------
__global__ void init_kernel(const float* __restrict__ h, const float* __restrict__ eiw,
                            const float* __restrict__ eib, float* __restrict__ hh,
                            float* __restrict__ x)
{
  int g = blockIdx.x * 256 + threadIdx.x;   // 16384*128
  int n = g >> 7, c = g & 127;
  float acc = eib[c];
  #pragma unroll
  for (int j = 0; j < 8; ++j) acc += h[n*11 + 3 + j] * eiw[j*128 + c];
  hh[g] = acc;
  if (c < 4) x[n*4 + c] = (c < 3) ? h[n*11 + c] * (1.0f/3330.0f) : 0.f;
}

// ---------------- embedding_out ----------------
__global__ void out_kernel(const float* __restrict__ hh, const float* __restrict__ x,
                           const float* __restrict__ ow, const float* __restrict__ ob,
                           float* __restrict__ out)
{
  int g = blockIdx.x * 256 + threadIdx.x;   // 16384*4
  int n = g >> 2, o = g & 3;
  float acc = ob[o];
  #pragma unroll 8
  for (int k = 0; k < 128; ++k) acc += hh[n*128 + k] * ow[k*4 + o];
  #pragma unroll
  for (int d = 0; d < 3; ++d) acc += x[n*4 + d] * ow[(128 + d)*4 + o];
  out[g] = acc;
}

// 80-row GEMM: D = silu(A @ W^T(+bias)), A in LDS bf16, W from global (pre-transposed [col][k])
template<int KS>
static __device__ __forceinline__ void gemm80_silu(
    const unsigned short* __restrict__ A, int astr,
    const unsigned short* __restrict__ W,
    const float* __restrict__ bias,
    unsigned short* __restrict__ D, int dstr,
    int wave, int lr, int lh)
{
  const int wstr = KS * 32;
  fv4 acc[5][2];
  #pragma unroll
  for (int m = 0; m < 5; ++m) { acc[m][0] = (fv4){0,0,0,0}; acc[m][1] = (fv4){0,0,0,0}; }
  #pragma unroll
  for (int ks = 0; ks < KS; ++ks) {
    bv8 b0 = *(const bv8*)(W + (wave*32      + lr)*wstr + ks*32 + lh*8);
    bv8 b1 = *(const bv8*)(W + (wave*32 + 16 + lr)*wstr + ks*32 + lh*8);
    #pragma unroll
    for (int m = 0; m < 5; ++m) {
      bv8 a = *(const bv8*)(A + (m*16 + lr)*astr + ks*32 + lh*8);
      acc[m][0] = MFMA(a, b0, acc[m][0]);
      acc[m][1] = MFMA(a, b1, acc[m][1]);
    }
  }
  #pragma unroll
  for (int m = 0; m < 5; ++m) {
    #pragma unroll
    for (int t = 0; t < 2; ++t) {
      int col = wave*32 + t*16 + lr;
      float bb = bias[col];
      #pragma unroll
      for (int j = 0; j < 4; ++j) {
        int row = m*16 + lh*4 + j;
        D[row*dstr + col] = f2b(silu_f(acc[m][t][j] + bb));
      }
    }
  }
}

// ---------------- one E_GCL layer, fully fused per block of 8 dst nodes ----------------
__global__ __launch_bounds__(256, 2) void layer_kernel(
    const int* __restrict__ idxp,
    const unsigned short* __restrict__ wt,        // this layer's weight base
    const float* __restrict__ eb1, const float* __restrict__ eb2,
    const float* __restrict__ cb1, const float* __restrict__ cw2,
    const float* __restrict__ nb1, const float* __restrict__ nb2,
    const float* __restrict__ hhin, float* __restrict__ hhout,
    const float* __restrict__ xin, float* __restrict__ xout)
{
  __shared__ __align__(16) unsigned char smem[67456];
  unsigned short* sA   = (unsigned short*)(smem);           // [80][168] ef0 (hh_src | radial | 0-pad)
  unsigned short* sEf  = (unsigned short*)(smem);           // [80][136] ef   (aliases sA after G1)
  unsigned short* sN1  = (unsigned short*)(smem + 21760);   // [16][136] node-MLP hidden
  unsigned short* sB   = (unsigned short*)(smem + 26880);   // [80][136] t1 -> c1
  unsigned short* sHHb = (unsigned short*)(smem + 48640);   // [16][136] hh_dst bf16 (rows 8..15 zero)
  unsigned short* sAg  = (unsigned short*)(smem + 52992);   // [16][136] sum_ef bf16 (rows 8..15 zero)
  float* sHC  = (float*)(smem + 57344);                     // [16][128] hh_dst @ W1d + b1
  float* sDiff= (float*)(smem + 65536);                     // [80][4]
  float* sCm  = (float*)(smem + 66816);                     // [80]
  int*   sIdx = (int*)(smem + 67136);                       // [80]

  const int tid  = threadIdx.x;
  const int wave = tid >> 6;
  const int lane = tid & 63;
  const int lr   = lane & 15;
  const int lh   = lane >> 4;
  const int node0 = blockIdx.x * TM;

  // ---- stage 1: idx, diff, radial, zero-pad ----
  if (tid < EDG) {
    int e = tid;
    int n = e / KNN;
    int s = idxp[node0*KNN + e];
    sIdx[e] = s;
    float xd0 = xin[(node0+n)*4+0], xd1 = xin[(node0+n)*4+1], xd2 = xin[(node0+n)*4+2];
    float d0 = xin[s*4+0] - xd0, d1 = xin[s*4+1] - xd1, d2 = xin[s*4+2] - xd2;
    sDiff[e*4+0] = d0; sDiff[e*4+1] = d1; sDiff[e*4+2] = d2;
    float rad = d0*d0 + d1*d1 + d2*d2;
    sA[e*168 + 128] = f2b(rad);
    #pragma unroll
    for (int c = 129; c < 160; ++c) sA[e*168 + c] = 0;
  }
  __syncthreads();

  // ---- stage 2: gather hh_src -> sA cols 0..127 (bf16) ----
  #pragma unroll
  for (int it = 0; it < 10; ++it) {
    int q = tid + it*256;          // 2560 quads
    int e = q >> 5, cq = q & 31;
    int s = sIdx[e];
    float4 v = *(const float4*)(hhin + s*HD + cq*4);
    ushort4 b; b.x = f2b(v.x); b.y = f2b(v.y); b.z = f2b(v.z); b.w = f2b(v.w);
    *(ushort4*)(sA + e*168 + cq*4) = b;
  }
  // ---- stage 3: hh_dst -> sHHb (rows 8..15 zero) ----
  #pragma unroll
  for (int it = 0; it < 2; ++it) {
    int q = tid + it*256;          // 512 quads: 16 rows x 32
    int r = q >> 5, cq = q & 31;
    ushort4 b;
    if (r < TM) {
      float4 v = *(const float4*)(hhin + (node0+r)*HD + cq*4);
      b.x = f2b(v.x); b.y = f2b(v.y); b.z = f2b(v.z); b.w = f2b(v.w);
    } else { b.x = b.y = b.z = b.w = 0; }
    *(ushort4*)(sHHb + r*136 + cq*4) = b;
  }
  // ---- stage 4: zero sAg rows 8..15 ----
  {
    int r = 8 + (tid >> 5), cq = tid & 31;
    ushort4 z; z.x = z.y = z.z = z.w = 0;
    *(ushort4*)(sAg + r*136 + cq*4) = z;
  }
  __syncthreads();

  // ---- hc = hh_dst @ W1d + b1  -> sHC [16][128] fp32 ----
  {
    const unsigned short* W = wt + W1D_OFF;
    #pragma unroll
    for (int t = 0; t < 2; ++t) {
      int col = (wave*2 + t)*16 + lr;
      fv4 acc = (fv4){0,0,0,0};
      #pragma unroll
      for (int ks = 0; ks < 4; ++ks) {
        bv8 a = *(const bv8*)(sHHb + lr*136 + ks*32 + lh*8);
        bv8 b = *(const bv8*)(W + col*128 + ks*32 + lh*8);
        acc = MFMA(a, b, acc);
      }
      float bias = eb1[col];
      #pragma unroll
      for (int j = 0; j < 4; ++j) sHC[(lh*4+j)*128 + col] = acc[j] + bias;
    }
  }
  __syncthreads();

  // ---- GEMM1: t1 = silu([hh_src|radial] @ W1e + hc) -> sB ----
  {
    const unsigned short* W = wt + W1E_OFF;
    fv4 acc[5][2];
    #pragma unroll
    for (int m = 0; m < 5; ++m) { acc[m][0] = (fv4){0,0,0,0}; acc[m][1] = (fv4){0,0,0,0}; }
    #pragma unroll
    for (int ks = 0; ks < 5; ++ks) {
      bv8 b0 = *(const bv8*)(W + (wave*32      + lr)*160 + ks*32 + lh*8);
      bv8 b1 = *(const bv8*)(W + (wave*32 + 16 + lr)*160 + ks*32 + lh*8);
      #pragma unroll
      for (int m = 0; m < 5; ++m) {
        bv8 a = *(const bv8*)(sA + (m*16 + lr)*168 + ks*32 + lh*8);
        acc[m][0] = MFMA(a, b0, acc[m][0]);
        acc[m][1] = MFMA(a, b1, acc[m][1]);
      }
    }
    #pragma unroll
    for (int m = 0; m < 5; ++m) {
      #pragma unroll
      for (int t = 0; t < 2; ++t) {
        int col = wave*32 + t*16 + lr;
        #pragma unroll
        for (int j = 0; j < 4; ++j) {
          int row = m*16 + lh*4 + j;
          int nd = row / 10;
          float v = acc[m][t][j] + sHC[nd*128 + col];
          sB[row*136 + col] = f2b(silu_f(v));
        }
      }
    }
  }
  __syncthreads();

  // ---- GEMM2: ef = silu(t1 @ W2 + b2) -> sEf (overwrites sA region) ----
  gemm80_silu<4>(sB, 136, wt + W2_OFF, eb2, sEf, 136, wave, lr, lh);
  __syncthreads();

  // ---- GEMM3: c1 = silu(ef @ C1 + cb1) -> sB ----
  gemm80_silu<4>(sEf, 136, wt + C1_OFF, cb1, sB, 136, wave, lr, lh);
  __syncthreads();

  // ---- cm = c1 @ cw2 (fp32 VALU) ; sum_ef -> sAg rows 0..7 ----
  if (tid < EDG) {
    float acc = 0.f;
    #pragma unroll 8
    for (int c = 0; c < 128; ++c) acc += b2f(sB[tid*136 + c]) * cw2[c];
    sCm[tid] = acc;
  }
  #pragma unroll
  for (int it = 0; it < 4; ++it) {
    int o = tid + it*256;           // 1024 = 8 nodes x 128
    int n = o >> 7, c = o & 127;
    float s = 0.f;
    #pragma unroll
    for (int k = 0; k < KNN; ++k) s += b2f(sEf[(n*KNN + k)*136 + c]);
    sAg[n*136 + c] = f2b(s);
  }
  __syncthreads();

  // ---- x update (fp32) ----
  if (tid < 3*TM) {
    int n = tid / 3, d = tid % 3;
    float xo = xin[(node0+n)*4 + d];
    xo = fminf(fmaxf(xo, -1000.f), 1000.f);
    float s = 0.f;
    #pragma unroll
    for (int k = 0; k < KNN; ++k) {
      float tr = sDiff[(n*KNN+k)*4 + d] * sCm[n*KNN + k];
      tr = fminf(fmaxf(tr, -1000.f), 1000.f);
      s += tr;
    }
    xout[(node0+n)*4 + d] = xo + s * (1.0f/KNN);
  } else if (tid < 4*TM) {
    xout[(node0 + (tid - 3*TM))*4 + 3] = 0.f;
  }
  // ---- node GEMM1: n1 = silu([hh | sum_ef] @ N1 + nb1) -> sN1 ----
  {
    const unsigned short* W = wt + N1_OFF;
    fv4 acc[2] = {(fv4){0,0,0,0}, (fv4){0,0,0,0}};
    #pragma unroll
    for (int ks = 0; ks < 8; ++ks) {
      const unsigned short* ap = (ks < 4) ? (sHHb + lr*136 + ks*32 + lh*8)
                                          : (sAg  + lr*136 + (ks-4)*32 + lh*8);
      bv8 a = *(const bv8*)ap;
      #pragma unroll
      for (int t = 0; t < 2; ++t) {
        bv8 b = *(const bv8*)(W + (wave*32 + t*16 + lr)*256 + ks*32 + lh*8);
        acc[t] = MFMA(a, b, acc[t]);
      }
    }
    #pragma unroll
    for (int t = 0; t < 2; ++t) {
      int col = wave*32 + t*16 + lr;
      float bb = nb1[col];
      #pragma unroll
      for (int j = 0; j < 4; ++j) {
        int row = lh*4 + j;
        sN1[row*136 + col] = f2b(silu_f(acc[t][j] + bb));
      }
    }
  }
  __syncthreads();

  // ---- node GEMM2: hh_out = hh_in + n1 @ N2 + nb2 ----
  {
    const unsigned short* W = wt + N2_OFF;
    fv4 acc[2] = {(fv4){0,0,0,0}, (fv4){0,0,0,0}};
    #pragma unroll
    for (int ks = 0; ks < 4; ++ks) {
      bv8 a = *(const bv8*)(sN1 + lr*136 + ks*32 + lh*8);
      #pragma unroll
      for (int t = 0; t < 2; ++t) {
        bv8 b = *(const bv8*)(W + (wave*32 + t*16 + lr)*128 + ks*32 + lh*8);
        acc[t] = MFMA(a, b, acc[t]);
      }
    }
    #pragma unroll
    for (int t = 0; t < 2; ++t) {
      int col = wave*32 + t*16 + lr;
      float bb = nb2[col];
      #pragma unroll
      for (int j = 0; j < 4; ++j) {
        int row = lh*4 + j;
        if (row < TM) {
          int g = (node0 + row)*HD + col;
          hhout[g] = hhin[g] + acc[t][j] + bb;
        }
      }
    }
  }
}

extern "C" void kernel_launch(void* const* d_in, const int* in_sizes, int n_in,
                              void* d_out, int out_size, void* d_ws, size_t ws_size,
                              hipStream_t stream)
{
  (void)in_sizes; (void)n_in; (void)out_size; (void)ws_size;
  const float* h   = (const float*)d_in[0];
  const int*   idx = (const int*)d_in[1];
  const float* eiw = (const float*)d_in[2];
  const float* eib = (const float*)d_in[3];
  const float* ew1 = (const float*)d_in[4];
  const float* eb1 = (const float*)d_in[5];
  const float* ew2 = (const float*)d_in[6];
  const float* eb2 = (const float*)d_in[7];
  const float* cw1 = (const float*)d_in[8];
  const float* cb1 = (const float*)d_in[9];
  const float* cw2 = (const float*)d_in[10];
  const float* nw1 = (const float*)d_in[11];
  const float* nb1 = (const float*)d_in[12];
  const float* nw2 = (const float*)d_in[13];
  const float* nb2 = (const float*)d_in[14];
  const float* eow = (const float*)d_in[15];
  const float* eob = (const float*)d_in[16];

  unsigned char* ws = (unsigned char*)d_ws;
  unsigned short* wt = (unsigned short*)ws;                    // 1,662,976 B
  float* hhA = (float*)(ws + 1662976);                         // 8 MB
  float* hhB = (float*)(ws + 1662976 + 8388608);
  float* xA  = (float*)(ws + 1662976 + 2*8388608);             // 256 KB
  float* xB  = (float*)(ws + 1662976 + 2*8388608 + 262144);

  prep_kernel<<<3248, 256, 0, stream>>>(ew1, ew2, cw1, nw1, nw2, wt);
  init_kernel<<<8192, 256, 0, stream>>>(h, eiw, eib, hhA, xA);

  float* hhs = hhA; float* hhd = hhB;
  float* xs  = xA;  float* xd  = xB;
  for (int l = 0; l < NL; ++l) {
    layer_kernel<<<NN/TM, 256, 0, stream>>>(idx, wt + (size_t)l*WL_STRIDE,
        eb1 + l*128, eb2 + l*128, cb1 + l*128, cw2 + l*128,
        nb1 + l*128, nb2 + l*128,
        hhs, hhd, xs, xd);
    float* t;
    t = hhs; hhs = hhd; hhd = t;
    t = xs;  xs  = xd;  xd  = t;
  }
  out_kernel<<<NN*4/256, 256, 0, stream>>>(hhs, xs, eow, eob, (float*)d_out);
}

// Round 2
// 584.747 us; speedup vs baseline: 1.2832x; 1.2832x over previous
//
#include <hip/hip_runtime.h>
#include <hip/hip_bf16.h>

#define NN 16384
#define KNN 10
#define HD 128
#define NL 7
#define TM 8
#define EDG 80   // TM*KNN

// per-layer bf16 weight layout offsets (elements)
#define W1E_OFF 0        // [128 col][128 k]   (k = hh_src rows 1..128 of w1)
#define W1D_OFF 16384    // [128][128]         (hh_dst rows 129..256)
#define W2_OFF  32768    // [128][128]
#define C1_OFF  49152    // [128][128]
#define N1_OFF  65536    // [128][256]
#define N2_OFF  98304    // [128][128]
#define WL_STRIDE 114688

typedef float fv4 __attribute__((ext_vector_type(4)));
typedef short bv8 __attribute__((ext_vector_type(8)));

static __device__ __forceinline__ unsigned short f2b(float f) {
  __hip_bfloat16 h = __float2bfloat16(f);
  return __builtin_bit_cast(unsigned short, h);
}
static __device__ __forceinline__ float b2f(unsigned short u) {
  unsigned int x = ((unsigned int)u) << 16;
  return __builtin_bit_cast(float, x);
}
static __device__ __forceinline__ float silu_f(float x) {
  return x / (1.0f + __expf(-x));
}
#define MFMA(a,b,c) __builtin_amdgcn_mfma_f32_16x16x32_bf16((a),(b),(c),0,0,0)

// XOR-swizzled LDS addressing: stride 128 shorts (256B = exactly 2 bank cycles).
// bank = f(col ^ 8*((row&7)^((row>>3)&7))) -> 2-way max on column-slice b128 reads,
// and spreads row-major per-lane reads (cm / sum_ef) too.
static __device__ __forceinline__ int swz(int row, int col) {
  return row * 128 + (col ^ ((((row & 7) ^ ((row >> 3) & 7))) << 3));
}

// ---------------- weight prep: fp32 -> bf16 transposed [col][k] ----------------
__global__ void prep_kernel(const float* __restrict__ ew1, const float* __restrict__ ew2,
                            const float* __restrict__ cw1, const float* __restrict__ nw1,
                            const float* __restrict__ nw2, unsigned short* __restrict__ wt)
{
  int g = blockIdx.x * 256 + threadIdx.x;
  if (g >= NL * WL_STRIDE) return;
  int l = g / WL_STRIDE;
  int r = g % WL_STRIDE;
  float v;
  if (r < 16384) {                       // W1e
    int c = r >> 7, k = r & 127;
    v = ew1[(l*257 + 1 + k)*128 + c];
  } else if (r < 32768) {                // W1d
    int q = r - 16384; int c = q >> 7, k = q & 127;
    v = ew1[(l*257 + 129 + k)*128 + c];
  } else if (r < 49152) {                // W2
    int q = r - 32768; int c = q >> 7, k = q & 127;
    v = ew2[(l*128 + k)*128 + c];
  } else if (r < 65536) {                // C1
    int q = r - 49152; int c = q >> 7, k = q & 127;
    v = cw1[(l*128 + k)*128 + c];
  } else if (r < 98304) {                // N1 [c][k0..255]
    int q = r - 65536; int c = q >> 8, k = q & 255;
    v = nw1[(l*256 + k)*128 + c];
  } else {                               // N2
    int q = r - 98304; int c = q >> 7, k = q & 127;
    v = nw2[(l*128 + k)*128 + c];
  }
  wt[g] = f2b(v);
}

// ---------------- embedding_in + x init (+ bf16 hh copy) ----------------
__global__ void init_kernel(const float* __restrict__ h, const float* __restrict__ eiw,
                            const float* __restrict__ eib, float* __restrict__ hh,
                            unsigned short* __restrict__ hhb, float* __restrict__ x)
{
  int g = blockIdx.x * 256 + threadIdx.x;   // 16384*128
  int n = g >> 7, c = g & 127;
  float acc = eib[c];
  #pragma unroll
  for (int j = 0; j < 8; ++j) acc += h[n*11 + 3 + j] * eiw[j*128 + c];
  hh[g] = acc;
  hhb[g] = f2b(acc);
  if (c < 4) x[n*4 + c] = (c < 3) ? h[n*11 + c] * (1.0f/3330.0f) : 0.f;
}

// ---------------- embedding_out ----------------
__global__ void out_kernel(const float* __restrict__ hh, const float* __restrict__ x,
                           const float* __restrict__ ow, const float* __restrict__ ob,
                           float* __restrict__ out)
{
  int g = blockIdx.x * 256 + threadIdx.x;   // 16384*4
  int n = g >> 2, o = g & 3;
  float acc = ob[o];
  #pragma unroll 8
  for (int k = 0; k < 128; ++k) acc += hh[n*128 + k] * ow[k*4 + o];
  #pragma unroll
  for (int d = 0; d < 3; ++d) acc += x[n*4 + d] * ow[(128 + d)*4 + o];
  out[g] = acc;
}

// 80-row GEMM: D = silu(A @ W^T + bias); A,D swizzled LDS bf16; W global [col][k]
static __device__ __forceinline__ void gemm80_silu(
    const unsigned short* __restrict__ A,
    const unsigned short* __restrict__ W,
    const float* __restrict__ bias,
    unsigned short* __restrict__ D,
    int wave, int lr, int lh)
{
  fv4 acc[5][2];
  #pragma unroll
  for (int m = 0; m < 5; ++m) { acc[m][0] = (fv4){0,0,0,0}; acc[m][1] = (fv4){0,0,0,0}; }
  #pragma unroll
  for (int ks = 0; ks < 4; ++ks) {
    bv8 b0 = *(const bv8*)(W + (wave*32      + lr)*128 + ks*32 + lh*8);
    bv8 b1 = *(const bv8*)(W + (wave*32 + 16 + lr)*128 + ks*32 + lh*8);
    #pragma unroll
    for (int m = 0; m < 5; ++m) {
      bv8 a = *(const bv8*)(A + swz(m*16 + lr, ks*32 + lh*8));
      acc[m][0] = MFMA(a, b0, acc[m][0]);
      acc[m][1] = MFMA(a, b1, acc[m][1]);
    }
  }
  #pragma unroll
  for (int m = 0; m < 5; ++m) {
    #pragma unroll
    for (int t = 0; t < 2; ++t) {
      int col = wave*32 + t*16 + lr;
      float bb = bias[col];
      #pragma unroll
      for (int j = 0; j < 4; ++j) {
        int row = m*16 + lh*4 + j;
        D[swz(row, col)] = f2b(silu_f(acc[m][t][j] + bb));
      }
    }
  }
}

// ---------------- one E_GCL layer, fused per block of 8 dst nodes ----------------
__global__ __launch_bounds__(256, 3) void layer_kernel(
    const int* __restrict__ idxp,
    const unsigned short* __restrict__ wt,
    const float* __restrict__ eb1, const float* __restrict__ eb2,
    const float* __restrict__ cb1, const float* __restrict__ cw2,
    const float* __restrict__ nb1, const float* __restrict__ nb2,
    const float* __restrict__ w1r0p,           // fp32 w1 row 0 (radial row)
    float* __restrict__ hh,                    // fp32 residual, updated in place
    const unsigned short* __restrict__ hhbin,  // bf16 hh copy (gather source)
    unsigned short* __restrict__ hhbout,
    const float* __restrict__ xin, float* __restrict__ xout)
{
  __shared__ __align__(16) unsigned char smem[53312];
  unsigned short* sA   = (unsigned short*)(smem);           // [80][128] hh_src -> ef
  unsigned short* sB   = (unsigned short*)(smem + 20480);   // [80][128] t1 -> c1 -> n1
  unsigned short* sHHb = (unsigned short*)(smem + 40960);   // [16][128] hh_dst (rows 8..15 zero)
  unsigned short* sAg  = (unsigned short*)(smem + 45056);   // [16][128] sum_ef (rows 8..15 zero)
  unsigned short* sHC  = (unsigned short*)(smem + 49152);   // [128 col][8 nd] bf16 transposed
  float* sDx  = (float*)(smem + 51200);
  float* sDy  = (float*)(smem + 51520);
  float* sDz  = (float*)(smem + 51840);
  float* sRad = (float*)(smem + 52160);
  float* sCm  = (float*)(smem + 52480);
  float* sCw2 = (float*)(smem + 52800);
  unsigned short* sEf = sA;
  unsigned short* sN1 = sB;

  const int tid  = threadIdx.x;
  const int wave = tid >> 6;
  const int lane = tid & 63;
  const int lr   = lane & 15;
  const int lh   = lane >> 4;
  const int node0 = blockIdx.x * TM;

  // ---- stage 1: diff/radial (fp32), cw2 -> LDS, zero pad rows ----
  if (tid < EDG) {
    int e = tid, n = e / KNN;
    int s = idxp[node0*KNN + e];
    float xd0 = xin[(node0+n)*4+0], xd1 = xin[(node0+n)*4+1], xd2 = xin[(node0+n)*4+2];
    float d0 = xin[s*4+0] - xd0, d1 = xin[s*4+1] - xd1, d2 = xin[s*4+2] - xd2;
    sDx[e] = d0; sDy[e] = d1; sDz[e] = d2;
    sRad[e] = d0*d0 + d1*d1 + d2*d2;
  } else if (tid < EDG + 128) {
    sCw2[tid - EDG] = cw2[tid - EDG];
  }
  {
    int r = 8 + ((tid >> 4) & 7);
    int c = (tid & 15) << 3;
    unsigned short* dst = (tid < 128) ? sHHb : sAg;
    bv8 z = {0,0,0,0,0,0,0,0};
    *(bv8*)(dst + swz(r, c)) = z;
  }
  // ---- stage 2: gather hh_src (bf16, no conversion) + hh_dst ----
  #pragma unroll
  for (int it = 0; it < 5; ++it) {
    int q = tid + it*256;                 // 1280 = 80 rows x 16 chunks
    int e = q >> 4, c = (q & 15) << 3;
    int s = idxp[node0*KNN + e];
    bv8 v = *(const bv8*)(hhbin + s*HD + c);
    *(bv8*)(sA + swz(e, c)) = v;
  }
  if (tid < 128) {                        // 8 rows x 16 chunks
    int r = tid >> 4, c = (tid & 15) << 3;
    bv8 v = *(const bv8*)(hhbin + (node0 + r)*HD + c);
    *(bv8*)(sHHb + swz(r, c)) = v;
  }
  __syncthreads();

  // ---- hc = hh_dst @ W1d + b1 -> sHC[col][nd] bf16 ----
  {
    const unsigned short* W = wt + W1D_OFF;
    #pragma unroll
    for (int t = 0; t < 2; ++t) {
      int col = wave*32 + t*16 + lr;
      fv4 acc = (fv4){0,0,0,0};
      #pragma unroll
      for (int ks = 0; ks < 4; ++ks) {
        bv8 a = *(const bv8*)(sHHb + swz(lr, ks*32 + lh*8));
        bv8 b = *(const bv8*)(W + col*128 + ks*32 + lh*8);
        acc = MFMA(a, b, acc);
      }
      if (lh < 2) {
        float bias = eb1[col];
        #pragma unroll
        for (int j = 0; j < 4; ++j)
          sHC[col*8 + lh*4 + j] = f2b(acc[j] + bias);
      }
    }
  }
  __syncthreads();

  // ---- GEMM1: t1 = silu(hh_src@W1e + hc + radial*w1row0) -> sB ----
  {
    const unsigned short* W = wt + W1E_OFF;
    float w1r0[2];
    #pragma unroll
    for (int t = 0; t < 2; ++t) w1r0[t] = w1r0p[wave*32 + t*16 + lr];
    fv4 acc[5][2];
    #pragma unroll
    for (int m = 0; m < 5; ++m) { acc[m][0] = (fv4){0,0,0,0}; acc[m][1] = (fv4){0,0,0,0}; }
    #pragma unroll
    for (int ks = 0; ks < 4; ++ks) {
      bv8 b0 = *(const bv8*)(W + (wave*32      + lr)*128 + ks*32 + lh*8);
      bv8 b1 = *(const bv8*)(W + (wave*32 + 16 + lr)*128 + ks*32 + lh*8);
      #pragma unroll
      for (int m = 0; m < 5; ++m) {
        bv8 a = *(const bv8*)(sA + swz(m*16 + lr, ks*32 + lh*8));
        acc[m][0] = MFMA(a, b0, acc[m][0]);
        acc[m][1] = MFMA(a, b1, acc[m][1]);
      }
    }
    #pragma unroll
    for (int m = 0; m < 5; ++m) {
      #pragma unroll
      for (int t = 0; t < 2; ++t) {
        int col = wave*32 + t*16 + lr;
        #pragma unroll
        for (int j = 0; j < 4; ++j) {
          int row = m*16 + lh*4 + j;
          int nd = row / KNN;
          float v = acc[m][t][j] + b2f(sHC[col*8 + nd]) + sRad[row]*w1r0[t];
          sB[swz(row, col)] = f2b(silu_f(v));
        }
      }
    }
  }
  __syncthreads();

  // ---- GEMM2: ef = silu(t1 @ W2 + b2) -> sEf (aliases sA) ----
  gemm80_silu(sB, wt + W2_OFF, eb2, sEf, wave, lr, lh);
  __syncthreads();

  // ---- GEMM3: c1 = silu(ef @ C1 + cb1) -> sB ----
  gemm80_silu(sEf, wt + C1_OFF, cb1, sB, wave, lr, lh);
  __syncthreads();

  // ---- cm (tids 0..79) || sum_ef (tids 128..255), vectorized LDS reads ----
  if (tid < EDG) {
    float acc = 0.f;
    #pragma unroll
    for (int cc = 0; cc < 16; ++cc) {
      bv8 v = *(const bv8*)(sB + swz(tid, cc*8));
      #pragma unroll
      for (int e8 = 0; e8 < 8; ++e8)
        acc += b2f((unsigned short)v[e8]) * sCw2[cc*8 + e8];
    }
    sCm[tid] = acc;
  } else if (tid >= 128) {
    int q = tid - 128;                    // 128 = 8 nodes x 16 chunks
    int n = q >> 4, c = (q & 15) << 3;
    float s[8] = {0,0,0,0,0,0,0,0};
    #pragma unroll
    for (int k = 0; k < KNN; ++k) {
      bv8 v = *(const bv8*)(sEf + swz(n*KNN + k, c));
      #pragma unroll
      for (int e8 = 0; e8 < 8; ++e8) s[e8] += b2f((unsigned short)v[e8]);
    }
    bv8 p;
    #pragma unroll
    for (int e8 = 0; e8 < 8; ++e8) p[e8] = (short)f2b(s[e8]);
    *(bv8*)(sAg + swz(n, c)) = p;
  }
  __syncthreads();

  // ---- x update (fp32) ----
  if (tid < 3*TM) {
    int n = tid / 3, d = tid % 3;
    const float* sD = (d == 0) ? sDx : (d == 1) ? sDy : sDz;
    float xo = xin[(node0+n)*4 + d];
    xo = fminf(fmaxf(xo, -1000.f), 1000.f);
    float s = 0.f;
    #pragma unroll
    for (int k = 0; k < KNN; ++k) {
      float tr = sD[n*KNN + k] * sCm[n*KNN + k];
      tr = fminf(fmaxf(tr, -1000.f), 1000.f);
      s += tr;
    }
    xout[(node0+n)*4 + d] = xo + s * (1.0f/KNN);
  } else if (tid < 4*TM) {
    xout[(node0 + (tid - 3*TM))*4 + 3] = 0.f;
  }

  // ---- node GEMM1: n1 = silu([hh_dst | sum_ef] @ N1 + nb1) -> sN1 (aliases sB) ----
  {
    const unsigned short* W = wt + N1_OFF;
    fv4 acc[2] = {(fv4){0,0,0,0}, (fv4){0,0,0,0}};
    #pragma unroll
    for (int ks = 0; ks < 8; ++ks) {
      bv8 a = (ks < 4) ? *(const bv8*)(sHHb + swz(lr, ks*32 + lh*8))
                       : *(const bv8*)(sAg  + swz(lr, (ks-4)*32 + lh*8));
      #pragma unroll
      for (int t = 0; t < 2; ++t) {
        bv8 b = *(const bv8*)(W + (wave*32 + t*16 + lr)*256 + ks*32 + lh*8);
        acc[t] = MFMA(a, b, acc[t]);
      }
    }
    #pragma unroll
    for (int t = 0; t < 2; ++t) {
      int col = wave*32 + t*16 + lr;
      float bb = nb1[col];
      #pragma unroll
      for (int j = 0; j < 4; ++j)
        sN1[swz(lh*4 + j, col)] = f2b(silu_f(acc[t][j] + bb));
    }
  }
  __syncthreads();

  // ---- node GEMM2: hh += n1 @ N2 + nb2 (fp32 residual in place, + bf16 copy out) ----
  {
    const unsigned short* W = wt + N2_OFF;
    fv4 acc[2] = {(fv4){0,0,0,0}, (fv4){0,0,0,0}};
    #pragma unroll
    for (int ks = 0; ks < 4; ++ks) {
      bv8 a = *(const bv8*)(sN1 + swz(lr, ks*32 + lh*8));
      #pragma unroll
      for (int t = 0; t < 2; ++t) {
        bv8 b = *(const bv8*)(W + (wave*32 + t*16 + lr)*128 + ks*32 + lh*8);
        acc[t] = MFMA(a, b, acc[t]);
      }
    }
    if (lh < 2) {
      #pragma unroll
      for (int t = 0; t < 2; ++t) {
        int col = wave*32 + t*16 + lr;
        float bb = nb2[col];
        #pragma unroll
        for (int j = 0; j < 4; ++j) {
          int row = lh*4 + j;
          int g = (node0 + row)*HD + col;
          float v = hh[g] + acc[t][j] + bb;
          hh[g] = v;
          hhbout[g] = f2b(v);
        }
      }
    }
  }
}

extern "C" void kernel_launch(void* const* d_in, const int* in_sizes, int n_in,
                              void* d_out, int out_size, void* d_ws, size_t ws_size,
                              hipStream_t stream)
{
  (void)in_sizes; (void)n_in; (void)out_size; (void)ws_size;
  const float* h   = (const float*)d_in[0];
  const int*   idx = (const int*)d_in[1];
  const float* eiw = (const float*)d_in[2];
  const float* eib = (const float*)d_in[3];
  const float* ew1 = (const float*)d_in[4];
  const float* eb1 = (const float*)d_in[5];
  const float* ew2 = (const float*)d_in[6];
  const float* eb2 = (const float*)d_in[7];
  const float* cw1 = (const float*)d_in[8];
  const float* cb1 = (const float*)d_in[9];
  const float* cw2 = (const float*)d_in[10];
  const float* nw1 = (const float*)d_in[11];
  const float* nb1 = (const float*)d_in[12];
  const float* nw2 = (const float*)d_in[13];
  const float* nb2 = (const float*)d_in[14];
  const float* eow = (const float*)d_in[15];
  const float* eob = (const float*)d_in[16];

  unsigned char* ws = (unsigned char*)d_ws;
  unsigned short* wt   = (unsigned short*)ws;                 // 1,605,632 B
  float*          hh   = (float*)(ws + 1605632);              // 8,388,608 B (in-place)
  unsigned short* hhbA = (unsigned short*)(ws + 9994240);     // 4,194,304 B
  unsigned short* hhbB = (unsigned short*)(ws + 14188544);    // 4,194,304 B
  float*          xA   = (float*)(ws + 18382848);             // 262,144 B
  float*          xB   = (float*)(ws + 18644992);             // 262,144 B

  prep_kernel<<<(NL*WL_STRIDE + 255)/256, 256, 0, stream>>>(ew1, ew2, cw1, nw1, nw2, wt);
  init_kernel<<<NN*HD/256, 256, 0, stream>>>(h, eiw, eib, hh, hhbA, xA);

  unsigned short* hbs = hhbA; unsigned short* hbd = hhbB;
  float* xs = xA; float* xd = xB;
  for (int l = 0; l < NL; ++l) {
    layer_kernel<<<NN/TM, 256, 0, stream>>>(idx, wt + (size_t)l*WL_STRIDE,
        eb1 + l*128, eb2 + l*128, cb1 + l*128, cw2 + l*128,
        nb1 + l*128, nb2 + l*128,
        ew1 + (size_t)l*257*128,
        hh, hbs, hbd, xs, xd);
    unsigned short* ht = hbs; hbs = hbd; hbd = ht;
    float* t = xs; xs = xd; xd = t;
  }
  out_kernel<<<NN*4/256, 256, 0, stream>>>(hh, xs, eow, eob, (float*)d_out);
}

// Round 3
// 535.724 us; speedup vs baseline: 1.4006x; 1.0915x over previous
//
#include <hip/hip_runtime.h>
#include <hip/hip_bf16.h>

#define NN 16384
#define KNN 10
#define HD 128
#define NL 7
#define TM 8
#define EDG 80   // TM*KNN

// per-layer bf16 weight layout offsets (elements)
#define W1E_OFF 0        // [128 col][128 k]   (k = hh_src rows 1..128 of w1)
#define W1D_OFF 16384    // [128][128]         (hh_dst rows 129..256)
#define W2_OFF  32768    // [128][128]
#define C1_OFF  49152    // [128][128]
#define N1_OFF  65536    // [128][256]
#define N2_OFF  98304    // [128][128]
#define WL_STRIDE 114688

typedef float fv4 __attribute__((ext_vector_type(4)));
typedef short bv8 __attribute__((ext_vector_type(8)));

static __device__ __forceinline__ unsigned short f2b(float f) {
  __hip_bfloat16 h = __float2bfloat16(f);
  return __builtin_bit_cast(unsigned short, h);
}
static __device__ __forceinline__ float b2f(unsigned short u) {
  unsigned int x = ((unsigned int)u) << 16;
  return __builtin_bit_cast(float, x);
}
// packed RNE bf16 pair: D.lo = bf16(lo), D.hi = bf16(hi)
static __device__ __forceinline__ unsigned int pk2(float lo, float hi) {
  unsigned int r;
  asm("v_cvt_pk_bf16_f32 %0, %1, %2" : "=v"(r) : "v"(lo), "v"(hi));
  return r;
}
static __device__ __forceinline__ float silu_f(float x) {
  return x * __builtin_amdgcn_rcpf(1.0f + __expf(-x));
}
#define MFMA(a,b,c) __builtin_amdgcn_mfma_f32_16x16x32_bf16((a),(b),(c),0,0,0)

// XOR-swizzled LDS addressing, stride 128 shorts
static __device__ __forceinline__ int swz(int row, int col) {
  return row * 128 + (col ^ ((((row & 7) ^ ((row >> 3) & 7))) << 3));
}

// ---------------- weight prep: fp32 -> bf16 transposed [col][k] ----------------
__global__ void prep_kernel(const float* __restrict__ ew1, const float* __restrict__ ew2,
                            const float* __restrict__ cw1, const float* __restrict__ nw1,
                            const float* __restrict__ nw2, unsigned short* __restrict__ wt)
{
  int g = blockIdx.x * 256 + threadIdx.x;
  if (g >= NL * WL_STRIDE) return;
  int l = g / WL_STRIDE;
  int r = g % WL_STRIDE;
  float v;
  if (r < 16384) {                       // W1e
    int c = r >> 7, k = r & 127;
    v = ew1[(l*257 + 1 + k)*128 + c];
  } else if (r < 32768) {                // W1d
    int q = r - 16384; int c = q >> 7, k = q & 127;
    v = ew1[(l*257 + 129 + k)*128 + c];
  } else if (r < 49152) {                // W2
    int q = r - 32768; int c = q >> 7, k = q & 127;
    v = ew2[(l*128 + k)*128 + c];
  } else if (r < 65536) {                // C1
    int q = r - 49152; int c = q >> 7, k = q & 127;
    v = cw1[(l*128 + k)*128 + c];
  } else if (r < 98304) {                // N1 [c][k0..255]
    int q = r - 65536; int c = q >> 8, k = q & 255;
    v = nw1[(l*256 + k)*128 + c];
  } else {                               // N2
    int q = r - 98304; int c = q >> 7, k = q & 127;
    v = nw2[(l*128 + k)*128 + c];
  }
  wt[g] = f2b(v);
}

// ---------------- embedding_in + x init (+ bf16 hh copy) ----------------
__global__ void init_kernel(const float* __restrict__ h, const float* __restrict__ eiw,
                            const float* __restrict__ eib, float* __restrict__ hh,
                            unsigned short* __restrict__ hhb, float* __restrict__ x)
{
  int g = blockIdx.x * 256 + threadIdx.x;   // 16384*128
  int n = g >> 7, c = g & 127;
  float acc = eib[c];
  #pragma unroll
  for (int j = 0; j < 8; ++j) acc += h[n*11 + 3 + j] * eiw[j*128 + c];
  hh[g] = acc;
  hhb[g] = f2b(acc);
  if (c < 4) x[n*4 + c] = (c < 3) ? h[n*11 + c] * (1.0f/3330.0f) : 0.f;
}

// ---------------- embedding_out ----------------
__global__ void out_kernel(const float* __restrict__ hh, const float* __restrict__ x,
                           const float* __restrict__ ow, const float* __restrict__ ob,
                           float* __restrict__ out)
{
  int g = blockIdx.x * 256 + threadIdx.x;   // 16384*4
  int n = g >> 2, o = g & 3;
  float acc = ob[o];
  #pragma unroll 8
  for (int k = 0; k < 128; ++k) acc += hh[n*128 + k] * ow[k*4 + o];
  #pragma unroll
  for (int d = 0; d < 3; ++d) acc += x[n*4 + d] * ow[(128 + d)*4 + o];
  out[g] = acc;
}

// per-wave B-fragment slice load: w[ks] = col (wave*32+lr), w[4+ks] = col (+16)
static __device__ __forceinline__ void load_w8(bv8* w, const unsigned short* __restrict__ W,
                                               int wave, int lr, int lh) {
  #pragma unroll
  for (int ks = 0; ks < 4; ++ks) {
    w[ks]     = *(const bv8*)(W + (wave*32      + lr)*128 + ks*32 + lh*8);
    w[4 + ks] = *(const bv8*)(W + (wave*32 + 16 + lr)*128 + ks*32 + lh*8);
  }
}

// 80-row GEMM: D = silu(A @ W + bias); bias folded into acc init; pk-bf16 stores
static __device__ __forceinline__ void gemm80_silu_w(
    const unsigned short* __restrict__ A, const bv8* w,
    const float* __restrict__ bias,
    unsigned short* __restrict__ D, int wave, int lr, int lh)
{
  float b0 = bias[wave*32 + lr], b1 = bias[wave*32 + 16 + lr];
  fv4 acc[5][2];
  #pragma unroll
  for (int m = 0; m < 5; ++m) {
    acc[m][0] = (fv4){b0,b0,b0,b0};
    acc[m][1] = (fv4){b1,b1,b1,b1};
  }
  #pragma unroll
  for (int ks = 0; ks < 4; ++ks) {
    #pragma unroll
    for (int m = 0; m < 5; ++m) {
      bv8 a = *(const bv8*)(A + swz(m*16 + lr, ks*32 + lh*8));
      acc[m][0] = MFMA(a, w[ks],   acc[m][0]);
      acc[m][1] = MFMA(a, w[4+ks], acc[m][1]);
    }
  }
  #pragma unroll
  for (int m = 0; m < 5; ++m) {
    #pragma unroll
    for (int t = 0; t < 2; ++t) {
      int col = wave*32 + t*16 + lr;
      int r0 = m*16 + lh*4;
      unsigned int p01 = pk2(silu_f(acc[m][t][0]), silu_f(acc[m][t][1]));
      unsigned int p23 = pk2(silu_f(acc[m][t][2]), silu_f(acc[m][t][3]));
      D[swz(r0+0, col)] = (unsigned short)p01;
      D[swz(r0+1, col)] = (unsigned short)(p01 >> 16);
      D[swz(r0+2, col)] = (unsigned short)p23;
      D[swz(r0+3, col)] = (unsigned short)(p23 >> 16);
    }
  }
}

// ---------------- one E_GCL layer, fused per block of 8 dst nodes ----------------
__global__ __launch_bounds__(256, 3) void layer_kernel(
    const int* __restrict__ idxp,
    const unsigned short* __restrict__ wt,
    const float* __restrict__ eb1, const float* __restrict__ eb2,
    const float* __restrict__ cb1, const float* __restrict__ cw2,
    const float* __restrict__ nb1, const float* __restrict__ nb2,
    const float* __restrict__ w1r0p,           // fp32 w1 row 0 (radial row)
    float* __restrict__ hh,                    // fp32 residual, in place
    const unsigned short* __restrict__ hhbin,  // bf16 hh copy (gather source)
    unsigned short* __restrict__ hhbout,
    const float* __restrict__ xin, float* __restrict__ xout)
{
  __shared__ __align__(16) unsigned char smem[51136];
  unsigned short* sA   = (unsigned short*)(smem);           // [80][128] hh_src -> ef
  unsigned short* sB   = (unsigned short*)(smem + 20480);   // [80][128] t1 -> c1 -> n1
  unsigned short* sHHb = (unsigned short*)(smem + 40960);   // [8][128] hh_dst (rows 8-15 read = garbage, harmless)
  unsigned short* sAg  = (unsigned short*)(smem + 43008);   // [8][128] sum_ef
  float* sHC  = (float*)(smem + 45056);                     // [8][132] fp32 hh_dst@W1d + b1
  float* sDx  = (float*)(smem + 49280);
  float* sDy  = (float*)(smem + 49600);
  float* sDz  = (float*)(smem + 49920);
  float* sRad = (float*)(smem + 50240);
  float* sCm  = (float*)(smem + 50560);
  unsigned short* sCw2b = (unsigned short*)(smem + 50880);  // [128] bf16
  unsigned short* sEf = sA;
  unsigned short* sN1 = sB;

  const int tid  = threadIdx.x;
  const int wave = tid >> 6;
  const int lane = tid & 63;
  const int lr   = lane & 15;
  const int lh   = lane >> 4;
  const int node0 = blockIdx.x * TM;

  // ---- early weight preloads (latency overlaps staging) ----
  bv8 wd[8], we[8];
  load_w8(wd, wt + W1D_OFF, wave, lr, lh);
  load_w8(we, wt + W1E_OFF, wave, lr, lh);
  float w1r0_0 = w1r0p[wave*32 + lr];
  float w1r0_1 = w1r0p[wave*32 + 16 + lr];

  // ---- stage 1: diff/radial fp32, cw2 bf16 ----
  if (tid < EDG) {
    int e = tid, n = e / KNN;
    int s = idxp[node0*KNN + e];
    float xd0 = xin[(node0+n)*4+0], xd1 = xin[(node0+n)*4+1], xd2 = xin[(node0+n)*4+2];
    float d0 = xin[s*4+0] - xd0, d1 = xin[s*4+1] - xd1, d2 = xin[s*4+2] - xd2;
    sDx[e] = d0; sDy[e] = d1; sDz[e] = d2;
    sRad[e] = d0*d0 + d1*d1 + d2*d2;
  } else if (tid < EDG + 128) {
    sCw2b[tid - EDG] = f2b(cw2[tid - EDG]);
  }
  // ---- stage 2: gather hh_src + hh_dst (bf16) ----
  #pragma unroll
  for (int it = 0; it < 5; ++it) {
    int q = tid + it*256;                 // 1280 = 80 rows x 16 chunks
    int e = q >> 4, c = (q & 15) << 3;
    int s = idxp[node0*KNN + e];
    bv8 v = *(const bv8*)(hhbin + s*HD + c);
    *(bv8*)(sA + swz(e, c)) = v;
  }
  if (tid < 128) {
    int r = tid >> 4, c = (tid & 15) << 3;
    bv8 v = *(const bv8*)(hhbin + (node0 + r)*HD + c);
    *(bv8*)(sHHb + swz(r, c)) = v;
  }
  __syncthreads();

  // ---- hc = hh_dst @ W1d + b1 -> sHC[8][132] fp32 (wave-local cols, no barrier) ----
  bv8 w2r[8]; load_w8(w2r, wt + W2_OFF, wave, lr, lh);   // prefetch W2
  {
    float b0 = eb1[wave*32 + lr], b1 = eb1[wave*32 + 16 + lr];
    fv4 hac[2] = {(fv4){b0,b0,b0,b0}, (fv4){b1,b1,b1,b1}};
    #pragma unroll
    for (int ks = 0; ks < 4; ++ks) {
      bv8 a = *(const bv8*)(sHHb + swz(lr, ks*32 + lh*8));  // rows 8-15 garbage -> D rows 8-15 discarded
      hac[0] = MFMA(a, wd[ks],   hac[0]);
      hac[1] = MFMA(a, wd[4+ks], hac[1]);
    }
    if (lh < 2) {
      #pragma unroll
      for (int t = 0; t < 2; ++t) {
        int col = wave*32 + t*16 + lr;
        #pragma unroll
        for (int j = 0; j < 4; ++j)
          sHC[(lh*4 + j)*132 + col] = hac[t][j];
      }
    }
  }

  // ---- GEMM1: t1 = silu(hh_src@W1e + hc + radial*w1row0) -> sB ----
  {
    fv4 acc[5][2];
    #pragma unroll
    for (int m = 0; m < 5; ++m) {
      #pragma unroll
      for (int t = 0; t < 2; ++t) {
        int col = wave*32 + t*16 + lr;
        float w1r0t = t ? w1r0_1 : w1r0_0;
        #pragma unroll
        for (int j = 0; j < 4; ++j) {
          int row = m*16 + lh*4 + j;
          int nd = row / KNN;
          acc[m][t][j] = sHC[nd*132 + col] + sRad[row]*w1r0t;
        }
      }
    }
    #pragma unroll
    for (int ks = 0; ks < 4; ++ks) {
      #pragma unroll
      for (int m = 0; m < 5; ++m) {
        bv8 a = *(const bv8*)(sA + swz(m*16 + lr, ks*32 + lh*8));
        acc[m][0] = MFMA(a, we[ks],   acc[m][0]);
        acc[m][1] = MFMA(a, we[4+ks], acc[m][1]);
      }
    }
    #pragma unroll
    for (int m = 0; m < 5; ++m) {
      #pragma unroll
      for (int t = 0; t < 2; ++t) {
        int col = wave*32 + t*16 + lr;
        int r0 = m*16 + lh*4;
        unsigned int p01 = pk2(silu_f(acc[m][t][0]), silu_f(acc[m][t][1]));
        unsigned int p23 = pk2(silu_f(acc[m][t][2]), silu_f(acc[m][t][3]));
        sB[swz(r0+0, col)] = (unsigned short)p01;
        sB[swz(r0+1, col)] = (unsigned short)(p01 >> 16);
        sB[swz(r0+2, col)] = (unsigned short)p23;
        sB[swz(r0+3, col)] = (unsigned short)(p23 >> 16);
      }
    }
  }
  __syncthreads();

  // ---- GEMM2: ef = silu(t1 @ W2 + b2) -> sA ; prefetch C1 ----
  bv8 c1r[8]; load_w8(c1r, wt + C1_OFF, wave, lr, lh);
  gemm80_silu_w(sB, w2r, eb2, sA, wave, lr, lh);
  __syncthreads();

  // ---- GEMM3: c1 = silu(ef @ C1 + cb1) -> sB ----
  gemm80_silu_w(sA, c1r, cb1, sB, wave, lr, lh);
  __syncthreads();

  // ---- P: prefetch N1; wave0: cm (MFMA vs cw2 column) + x-update; waves2,3: sum_ef ----
  bv8 n1r[16];
  #pragma unroll
  for (int ks = 0; ks < 8; ++ks) {
    n1r[ks]     = *(const bv8*)(wt + N1_OFF + (wave*32      + lr)*256 + ks*32 + lh*8);
    n1r[8 + ks] = *(const bv8*)(wt + N1_OFF + (wave*32 + 16 + lr)*256 + ks*32 + lh*8);
  }
  if (wave == 0) {
    bv8 cw[4];
    #pragma unroll
    for (int ks = 0; ks < 4; ++ks) {
      bv8 z = {0,0,0,0,0,0,0,0};
      cw[ks] = z;
      if (lr == 0) cw[ks] = *(const bv8*)(sCw2b + ks*32 + lh*8);
    }
    fv4 am[5];
    #pragma unroll
    for (int m = 0; m < 5; ++m) am[m] = (fv4){0,0,0,0};
    #pragma unroll
    for (int ks = 0; ks < 4; ++ks) {
      #pragma unroll
      for (int m = 0; m < 5; ++m) {
        bv8 a = *(const bv8*)(sB + swz(m*16 + lr, ks*32 + lh*8));
        am[m] = MFMA(a, cw[ks], am[m]);
      }
    }
    if (lr == 0) {
      #pragma unroll
      for (int m = 0; m < 5; ++m)
        #pragma unroll
        for (int j = 0; j < 4; ++j)
          sCm[m*16 + lh*4 + j] = am[m][j];
    }
    if (lane < 24) {
      int n = lane / 3, d = lane % 3;
      const float* sD = (d == 0) ? sDx : (d == 1) ? sDy : sDz;
      float xo = xin[(node0+n)*4 + d];
      xo = fminf(fmaxf(xo, -1000.f), 1000.f);
      float s = 0.f;
      #pragma unroll
      for (int k = 0; k < KNN; ++k) {
        float tr = sD[n*KNN + k] * sCm[n*KNN + k];
        tr = fminf(fmaxf(tr, -1000.f), 1000.f);
        s += tr;
      }
      xout[(node0+n)*4 + d] = xo + s * (1.0f/KNN);
    } else if (lane < 32) {
      xout[(node0 + lane - 24)*4 + 3] = 0.f;
    }
  } else if (tid >= 128) {
    int q = tid - 128;                    // 128 = 8 nodes x 16 chunks
    int n = q >> 4, c = (q & 15) << 3;
    float s[8] = {0,0,0,0,0,0,0,0};
    #pragma unroll
    for (int k = 0; k < KNN; ++k) {
      bv8 v = *(const bv8*)(sEf + swz(n*KNN + k, c));
      #pragma unroll
      for (int e8 = 0; e8 < 8; ++e8) s[e8] += b2f((unsigned short)v[e8]);
    }
    unsigned int p0 = pk2(s[0], s[1]), p1 = pk2(s[2], s[3]);
    unsigned int p2 = pk2(s[4], s[5]), p3 = pk2(s[6], s[7]);
    uint4 pv = make_uint4(p0, p1, p2, p3);
    *(uint4*)(sAg + swz(n, c)) = pv;
  }
  __syncthreads();

  // ---- node GEMM1: n1 = silu([hh_dst | sum_ef] @ N1 + nb1) -> sN1 ; prefetch N2 ----
  bv8 n2r[8]; load_w8(n2r, wt + N2_OFF, wave, lr, lh);
  {
    float b0 = nb1[wave*32 + lr], b1 = nb1[wave*32 + 16 + lr];
    fv4 acc[2] = {(fv4){b0,b0,b0,b0}, (fv4){b1,b1,b1,b1}};
    #pragma unroll
    for (int ks = 0; ks < 8; ++ks) {
      bv8 a = (ks < 4) ? *(const bv8*)(sHHb + swz(lr, ks*32 + lh*8))
                       : *(const bv8*)(sAg  + swz(lr, (ks-4)*32 + lh*8));
      acc[0] = MFMA(a, n1r[ks],   acc[0]);
      acc[1] = MFMA(a, n1r[8+ks], acc[1]);
    }
    #pragma unroll
    for (int t = 0; t < 2; ++t) {
      int col = wave*32 + t*16 + lr;
      int r0 = lh*4;
      unsigned int p01 = pk2(silu_f(acc[t][0]), silu_f(acc[t][1]));
      unsigned int p23 = pk2(silu_f(acc[t][2]), silu_f(acc[t][3]));
      sN1[swz(r0+0, col)] = (unsigned short)p01;
      sN1[swz(r0+1, col)] = (unsigned short)(p01 >> 16);
      sN1[swz(r0+2, col)] = (unsigned short)p23;
      sN1[swz(r0+3, col)] = (unsigned short)(p23 >> 16);
    }
  }
  __syncthreads();

  // ---- node GEMM2: hh += n1 @ N2 + nb2 (fp32 residual in place + bf16 copy) ----
  {
    float b0 = nb2[wave*32 + lr], b1 = nb2[wave*32 + 16 + lr];
    fv4 acc[2] = {(fv4){b0,b0,b0,b0}, (fv4){b1,b1,b1,b1}};
    float hv[2][4];
    if (lh < 2) {
      #pragma unroll
      for (int t = 0; t < 2; ++t) {
        int col = wave*32 + t*16 + lr;
        #pragma unroll
        for (int j = 0; j < 4; ++j)
          hv[t][j] = hh[(node0 + lh*4 + j)*HD + col];
      }
    }
    #pragma unroll
    for (int ks = 0; ks < 4; ++ks) {
      bv8 a = *(const bv8*)(sN1 + swz(lr, ks*32 + lh*8));
      acc[0] = MFMA(a, n2r[ks],   acc[0]);
      acc[1] = MFMA(a, n2r[4+ks], acc[1]);
    }
    if (lh < 2) {
      #pragma unroll
      for (int t = 0; t < 2; ++t) {
        int col = wave*32 + t*16 + lr;
        #pragma unroll
        for (int j = 0; j < 4; ++j) {
          int g = (node0 + lh*4 + j)*HD + col;
          float v = hv[t][j] + acc[t][j];
          hh[g] = v;
          hhbout[g] = f2b(v);
        }
      }
    }
  }
}

extern "C" void kernel_launch(void* const* d_in, const int* in_sizes, int n_in,
                              void* d_out, int out_size, void* d_ws, size_t ws_size,
                              hipStream_t stream)
{
  (void)in_sizes; (void)n_in; (void)out_size; (void)ws_size;
  const float* h   = (const float*)d_in[0];
  const int*   idx = (const int*)d_in[1];
  const float* eiw = (const float*)d_in[2];
  const float* eib = (const float*)d_in[3];
  const float* ew1 = (const float*)d_in[4];
  const float* eb1 = (const float*)d_in[5];
  const float* ew2 = (const float*)d_in[6];
  const float* eb2 = (const float*)d_in[7];
  const float* cw1 = (const float*)d_in[8];
  const float* cb1 = (const float*)d_in[9];
  const float* cw2 = (const float*)d_in[10];
  const float* nw1 = (const float*)d_in[11];
  const float* nb1 = (const float*)d_in[12];
  const float* nw2 = (const float*)d_in[13];
  const float* nb2 = (const float*)d_in[14];
  const float* eow = (const float*)d_in[15];
  const float* eob = (const float*)d_in[16];

  unsigned char* ws = (unsigned char*)d_ws;
  unsigned short* wt   = (unsigned short*)ws;                 // 1,605,632 B
  float*          hh   = (float*)(ws + 1605632);              // 8,388,608 B (in-place)
  unsigned short* hhbA = (unsigned short*)(ws + 9994240);     // 4,194,304 B
  unsigned short* hhbB = (unsigned short*)(ws + 14188544);    // 4,194,304 B
  float*          xA   = (float*)(ws + 18382848);             // 262,144 B
  float*          xB   = (float*)(ws + 18644992);             // 262,144 B

  prep_kernel<<<(NL*WL_STRIDE + 255)/256, 256, 0, stream>>>(ew1, ew2, cw1, nw1, nw2, wt);
  init_kernel<<<NN*HD/256, 256, 0, stream>>>(h, eiw, eib, hh, hhbA, xA);

  unsigned short* hbs = hhbA; unsigned short* hbd = hhbB;
  float* xs = xA; float* xd = xB;
  for (int l = 0; l < NL; ++l) {
    layer_kernel<<<NN/TM, 256, 0, stream>>>(idx, wt + (size_t)l*WL_STRIDE,
        eb1 + l*128, eb2 + l*128, cb1 + l*128, cw2 + l*128,
        nb1 + l*128, nb2 + l*128,
        ew1 + (size_t)l*257*128,
        hh, hbs, hbd, xs, xd);
    unsigned short* ht = hbs; hbs = hbd; hbd = ht;
    float* t = xs; xs = xd; xd = t;
  }
  out_kernel<<<NN*4/256, 256, 0, stream>>>(hh, xs, eow, eob, (float*)d_out);
}

// Round 4
// 510.329 us; speedup vs baseline: 1.4703x; 1.0498x over previous
//
#include <hip/hip_runtime.h>
#include <hip/hip_bf16.h>

#define NN 16384
#define KNN 10
#define HD 128
#define NL 7
#define TM 8
#define EDG 80   // TM*KNN

// per-layer bf16 weight layout offsets (elements), all [outcol][k] (= W^T rows)
#define W1E_OFF 0
#define W1D_OFF 16384
#define W2_OFF  32768
#define C1_OFF  49152
#define N1_OFF  65536    // [outcol][256]
#define N2_OFF  98304
#define WL_STRIDE 114688

typedef float fv4 __attribute__((ext_vector_type(4)));
typedef short bv8 __attribute__((ext_vector_type(8)));

static __device__ __forceinline__ unsigned short f2b(float f) {
  __hip_bfloat16 h = __float2bfloat16(f);
  return __builtin_bit_cast(unsigned short, h);
}
static __device__ __forceinline__ float b2f(unsigned short u) {
  unsigned int x = ((unsigned int)u) << 16;
  return __builtin_bit_cast(float, x);
}
static __device__ __forceinline__ unsigned int pk2(float lo, float hi) {
  unsigned int r;
  asm("v_cvt_pk_bf16_f32 %0, %1, %2" : "=v"(r) : "v"(lo), "v"(hi));
  return r;
}
static __device__ __forceinline__ float silu_f(float x) {
  return x * __builtin_amdgcn_rcpf(1.0f + __expf(-x));
}
#define MFMA(a,b,c) __builtin_amdgcn_mfma_f32_16x16x32_bf16((a),(b),(c),0,0,0)

// activation LDS layout: [row 80/16][col 128], col XOR'd by (row&7)<<3.
// Preserves 8-short alignment (b128/b64 stay vectorized); spreads banks so
// B-frag b128 reads and b64 epilogue writes are conflict-free.
static __device__ __forceinline__ int swz8(int row, int col) {
  return row * 128 + (col ^ ((row & 7) << 3));
}

// ---------------- weight prep: fp32 -> bf16 transposed [outcol][k] ----------------
__global__ void prep_kernel(const float* __restrict__ ew1, const float* __restrict__ ew2,
                            const float* __restrict__ cw1, const float* __restrict__ nw1,
                            const float* __restrict__ nw2, unsigned short* __restrict__ wt)
{
  int g = blockIdx.x * 256 + threadIdx.x;
  if (g >= NL * WL_STRIDE) return;
  int l = g / WL_STRIDE;
  int r = g % WL_STRIDE;
  float v;
  if (r < 16384) {                       // W1e
    int c = r >> 7, k = r & 127;
    v = ew1[(l*257 + 1 + k)*128 + c];
  } else if (r < 32768) {                // W1d
    int q = r - 16384; int c = q >> 7, k = q & 127;
    v = ew1[(l*257 + 129 + k)*128 + c];
  } else if (r < 49152) {                // W2
    int q = r - 32768; int c = q >> 7, k = q & 127;
    v = ew2[(l*128 + k)*128 + c];
  } else if (r < 65536) {                // C1
    int q = r - 49152; int c = q >> 7, k = q & 127;
    v = cw1[(l*128 + k)*128 + c];
  } else if (r < 98304) {                // N1 [c][k0..255]
    int q = r - 65536; int c = q >> 8, k = q & 255;
    v = nw1[(l*256 + k)*128 + c];
  } else {                               // N2
    int q = r - 98304; int c = q >> 7, k = q & 127;
    v = nw2[(l*128 + k)*128 + c];
  }
  wt[g] = f2b(v);
}

// ---------------- embedding_in + x init (+ bf16 hh copy) ----------------
__global__ void init_kernel(const float* __restrict__ h, const float* __restrict__ eiw,
                            const float* __restrict__ eib, float* __restrict__ hh,
                            unsigned short* __restrict__ hhb, float* __restrict__ x)
{
  int g = blockIdx.x * 256 + threadIdx.x;   // 16384*128
  int n = g >> 7, c = g & 127;
  float acc = eib[c];
  #pragma unroll
  for (int j = 0; j < 8; ++j) acc += h[n*11 + 3 + j] * eiw[j*128 + c];
  hh[g] = acc;
  hhb[g] = f2b(acc);
  if (c < 3) x[n*4 + c] = h[n*11 + c] * (1.0f/3330.0f);
  if (c == 3) x[n*4 + 3] = 0.f;
}

// ---------------- embedding_out ----------------
__global__ void out_kernel(const float* __restrict__ hh, const float* __restrict__ x,
                           const float* __restrict__ ow, const float* __restrict__ ob,
                           float* __restrict__ out)
{
  int g = blockIdx.x * 256 + threadIdx.x;   // 16384*4
  int n = g >> 2, o = g & 3;
  float acc = ob[o];
  #pragma unroll 8
  for (int k = 0; k < 128; ++k) acc += hh[n*128 + k] * ow[k*4 + o];
  #pragma unroll
  for (int d = 0; d < 3; ++d) acc += x[n*4 + d] * ow[(128 + d)*4 + o];
  out[g] = acc;
}

// A-frag (weight) slice: w[ks] = outcol (wave*32+lr), w[4+ks] = outcol (+16)
static __device__ __forceinline__ void load_w8(bv8* w, const unsigned short* __restrict__ W,
                                               int wave, int lr, int lh) {
  #pragma unroll
  for (int ks = 0; ks < 4; ++ks) {
    w[ks]     = *(const bv8*)(W + (wave*32      + lr)*128 + ks*32 + lh*8);
    w[4 + ks] = *(const bv8*)(W + (wave*32 + 16 + lr)*128 + ks*32 + lh*8);
  }
}

// transposed 80-edge GEMM: D[e][c] = silu(bias[c] + sum_k W^T[c][k]*act[e][k])
static __device__ __forceinline__ void gemmT_silu(
    const unsigned short* __restrict__ act, const bv8* w,
    const float* __restrict__ bias, unsigned short* __restrict__ D,
    int cb0, int lr, int lh)
{
  fv4 bb0 = *(const fv4*)(bias + cb0);
  fv4 bb1 = *(const fv4*)(bias + cb0 + 16);
  fv4 acc[5][2];
  #pragma unroll
  for (int n = 0; n < 5; ++n) { acc[n][0] = bb0; acc[n][1] = bb1; }
  #pragma unroll
  for (int ks = 0; ks < 4; ++ks) {
    #pragma unroll
    for (int n = 0; n < 5; ++n) {
      bv8 b = *(const bv8*)(act + swz8(n*16 + lr, ks*32 + lh*8));
      acc[n][0] = MFMA(w[ks],   b, acc[n][0]);
      acc[n][1] = MFMA(w[4+ks], b, acc[n][1]);
    }
  }
  #pragma unroll
  for (int n = 0; n < 5; ++n) {
    int e = n*16 + lr;
    #pragma unroll
    for (int mt = 0; mt < 2; ++mt) {
      uint2 p;
      p.x = pk2(silu_f(acc[n][mt][0]), silu_f(acc[n][mt][1]));
      p.y = pk2(silu_f(acc[n][mt][2]), silu_f(acc[n][mt][3]));
      *(uint2*)(D + swz8(e, cb0 + mt*16)) = p;
    }
  }
}

// ---------------- one E_GCL layer, fused per block of 8 dst nodes ----------------
__global__ __launch_bounds__(256, 3) void layer_kernel(
    const int* __restrict__ idxp,
    const unsigned short* __restrict__ wt,
    const float* __restrict__ eb1, const float* __restrict__ eb2,
    const float* __restrict__ cb1, const float* __restrict__ cw2,
    const float* __restrict__ nb1, const float* __restrict__ nb2,
    const float* __restrict__ w1r0p,           // fp32 w1 row 0 (radial row)
    float* __restrict__ hh,                    // fp32 residual, in place
    const unsigned short* __restrict__ hhbin,  // bf16 hh copy (gather source)
    unsigned short* __restrict__ hhbout,
    const float* __restrict__ xin, float* __restrict__ xout)
{
  __shared__ __align__(16) unsigned char smem[50816];
  unsigned short* sA   = (unsigned short*)(smem);           // [80][128] hh_src -> ef
  unsigned short* sB   = (unsigned short*)(smem + 20480);   // [80][128] t1 -> c1 -> n1
  unsigned short* sHHb = (unsigned short*)(smem + 40960);   // [16][128] rows 8-15 garbage
  float*          sHC  = (float*)(smem + 45056);            // [8][132] fp32 (G1 only), aliased with:
  unsigned short* sAg  = (unsigned short*)(smem + 45056);   // [8][128] sum_ef (P -> nodeG1)
  float*          sCm  = (float*)(smem + 47104);            // [80]     (P only)
  float* sDx  = (float*)(smem + 49280);
  float* sDy  = (float*)(smem + 49600);
  float* sDz  = (float*)(smem + 49920);
  float* sRad = (float*)(smem + 50240);
  unsigned short* sCw2b = (unsigned short*)(smem + 50560);  // [128] bf16
  unsigned short* sEf = sA;
  unsigned short* sN1 = sB;

  const int tid  = threadIdx.x;
  const int wave = tid >> 6;
  const int lane = tid & 63;
  const int lr   = lane & 15;
  const int lh   = lane >> 4;
  const int cb0  = wave*32 + lh*4;      // this lane's D-row (out-channel) base, mt=0
  const int node0 = blockIdx.x * TM;

  // ---- early A-frag (weight) preloads: latency overlaps staging ----
  bv8 wd[8], we[8];
  load_w8(wd, wt + W1D_OFF, wave, lr, lh);
  load_w8(we, wt + W1E_OFF, wave, lr, lh);
  fv4 w1r0v[2];
  w1r0v[0] = *(const fv4*)(w1r0p + cb0);
  w1r0v[1] = *(const fv4*)(w1r0p + cb0 + 16);

  // ---- stage 1: diff/radial fp32, cw2 bf16 ----
  if (tid < EDG) {
    int e = tid, n = e / KNN;
    int s = idxp[node0*KNN + e];
    fv4 xs4 = *(const fv4*)(xin + s*4);
    fv4 xd4 = *(const fv4*)(xin + (node0+n)*4);
    float d0 = xs4[0]-xd4[0], d1 = xs4[1]-xd4[1], d2 = xs4[2]-xd4[2];
    sDx[e] = d0; sDy[e] = d1; sDz[e] = d2;
    sRad[e] = d0*d0 + d1*d1 + d2*d2;
  } else if (tid < EDG + 128) {
    sCw2b[tid - EDG] = f2b(cw2[tid - EDG]);
  }
  // ---- stage 2: gather hh_src + hh_dst (bf16) ----
  #pragma unroll
  for (int it = 0; it < 5; ++it) {
    int q = tid + it*256;                 // 1280 = 80 rows x 16 chunks
    int e = q >> 4, c = (q & 15) << 3;
    int s = idxp[node0*KNN + e];
    bv8 v = *(const bv8*)(hhbin + s*HD + c);
    *(bv8*)(sA + swz8(e, c)) = v;
  }
  if (tid < 128) {
    int r = tid >> 4, c = (tid & 15) << 3;
    bv8 v = *(const bv8*)(hhbin + (node0 + r)*HD + c);
    *(bv8*)(sHHb + swz8(r, c)) = v;
  }
  __syncthreads();

  // ---- hc^T = W1d^T @ hh_dst^T + b1 -> sHC[nd][c] fp32 (wave-local cols, no barrier) ----
  bv8 w2r[8]; load_w8(w2r, wt + W2_OFF, wave, lr, lh);   // prefetch W2
  {
    fv4 hac[2];
    hac[0] = *(const fv4*)(eb1 + cb0);
    hac[1] = *(const fv4*)(eb1 + cb0 + 16);
    #pragma unroll
    for (int ks = 0; ks < 4; ++ks) {
      bv8 b = *(const bv8*)(sHHb + swz8(lr, ks*32 + lh*8));  // rows 8-15 garbage -> cols 8-15 discarded
      hac[0] = MFMA(wd[ks],   b, hac[0]);
      hac[1] = MFMA(wd[4+ks], b, hac[1]);
    }
    if (lr < 8) {
      *(fv4*)(sHC + lr*132 + cb0)      = hac[0];
      *(fv4*)(sHC + lr*132 + cb0 + 16) = hac[1];
    }
  }

  // ---- GEMM1: t1[e][c] = silu(W1e^T@hh_src^T + hc + radial*w1row0) -> sB ----
  {
    fv4 acc[5][2];
    #pragma unroll
    for (int n = 0; n < 5; ++n) {
      int e = n*16 + lr;
      int nd = e / KNN;
      float rad = sRad[e];
      fv4 h0 = *(const fv4*)(sHC + nd*132 + cb0);
      fv4 h1 = *(const fv4*)(sHC + nd*132 + cb0 + 16);
      acc[n][0] = h0 + w1r0v[0]*rad;
      acc[n][1] = h1 + w1r0v[1]*rad;
    }
    #pragma unroll
    for (int ks = 0; ks < 4; ++ks) {
      #pragma unroll
      for (int n = 0; n < 5; ++n) {
        bv8 b = *(const bv8*)(sA + swz8(n*16 + lr, ks*32 + lh*8));
        acc[n][0] = MFMA(we[ks],   b, acc[n][0]);
        acc[n][1] = MFMA(we[4+ks], b, acc[n][1]);
      }
    }
    #pragma unroll
    for (int n = 0; n < 5; ++n) {
      int e = n*16 + lr;
      #pragma unroll
      for (int mt = 0; mt < 2; ++mt) {
        uint2 p;
        p.x = pk2(silu_f(acc[n][mt][0]), silu_f(acc[n][mt][1]));
        p.y = pk2(silu_f(acc[n][mt][2]), silu_f(acc[n][mt][3]));
        *(uint2*)(sB + swz8(e, cb0 + mt*16)) = p;
      }
    }
  }
  __syncthreads();

  // ---- GEMM2: ef = silu(W2^T @ t1^T + b2) -> sA ; prefetch C1 ----
  bv8 c1r[8]; load_w8(c1r, wt + C1_OFF, wave, lr, lh);
  gemmT_silu(sB, w2r, eb2, sA, cb0, lr, lh);
  __syncthreads();

  // ---- GEMM3: c1 = silu(C1^T @ ef^T + cb1) -> sB ----
  gemmT_silu(sA, c1r, cb1, sB, cb0, lr, lh);
  __syncthreads();

  // ---- P: prefetch N1; wave0: cm (MFMA vs cw2 col) + x-update; waves2,3: sum_ef ----
  bv8 n1r[16];
  #pragma unroll
  for (int ks = 0; ks < 8; ++ks) {
    n1r[ks]     = *(const bv8*)(wt + N1_OFF + (wave*32      + lr)*256 + ks*32 + lh*8);
    n1r[8 + ks] = *(const bv8*)(wt + N1_OFF + (wave*32 + 16 + lr)*256 + ks*32 + lh*8);
  }
  if (wave == 0) {
    bv8 cw[4];
    #pragma unroll
    for (int ks = 0; ks < 4; ++ks) {
      bv8 z = {0,0,0,0,0,0,0,0};
      cw[ks] = z;
      if (lr == 0) cw[ks] = *(const bv8*)(sCw2b + ks*32 + lh*8);
    }
    fv4 am[5];
    #pragma unroll
    for (int m = 0; m < 5; ++m) am[m] = (fv4){0,0,0,0};
    #pragma unroll
    for (int ks = 0; ks < 4; ++ks) {
      #pragma unroll
      for (int m = 0; m < 5; ++m) {
        bv8 a = *(const bv8*)(sB + swz8(m*16 + lr, ks*32 + lh*8));
        am[m] = MFMA(a, cw[ks], am[m]);   // activations as A here: D rows = edges
      }
    }
    if (lr == 0) {
      #pragma unroll
      for (int m = 0; m < 5; ++m)
        #pragma unroll
        for (int j = 0; j < 4; ++j)
          sCm[m*16 + lh*4 + j] = am[m][j];
    }
    if (lane < 24) {
      int n = lane / 3, d = lane % 3;
      const float* sD = (d == 0) ? sDx : (d == 1) ? sDy : sDz;
      float xo = xin[(node0+n)*4 + d];
      xo = fminf(fmaxf(xo, -1000.f), 1000.f);
      float s = 0.f;
      #pragma unroll
      for (int k = 0; k < KNN; ++k) {
        float tr = sD[n*KNN + k] * sCm[n*KNN + k];
        tr = fminf(fmaxf(tr, -1000.f), 1000.f);
        s += tr;
      }
      xout[(node0+n)*4 + d] = xo + s * (1.0f/KNN);
    }
  } else if (tid >= 128) {
    int q = tid - 128;                    // 128 = 8 nodes x 16 chunks
    int n = q >> 4, c = (q & 15) << 3;
    float s[8] = {0,0,0,0,0,0,0,0};
    #pragma unroll
    for (int k = 0; k < KNN; ++k) {
      bv8 v = *(const bv8*)(sEf + swz8(n*KNN + k, c));
      #pragma unroll
      for (int e8 = 0; e8 < 8; ++e8) s[e8] += b2f((unsigned short)v[e8]);
    }
    uint4 pv = make_uint4(pk2(s[0], s[1]), pk2(s[2], s[3]),
                          pk2(s[4], s[5]), pk2(s[6], s[7]));
    *(uint4*)(sAg + swz8(n, c)) = pv;
  }
  __syncthreads();

  // ---- node GEMM1: n1[nd][c] = silu(N1^T @ [hh_dst|sum_ef]^T + nb1) -> sN1 ; prefetch N2 ----
  bv8 n2r[8]; load_w8(n2r, wt + N2_OFF, wave, lr, lh);
  {
    fv4 acc[2];
    acc[0] = *(const fv4*)(nb1 + cb0);
    acc[1] = *(const fv4*)(nb1 + cb0 + 16);
    #pragma unroll
    for (int ks = 0; ks < 8; ++ks) {
      bv8 b = (ks < 4) ? *(const bv8*)(sHHb + swz8(lr, ks*32 + lh*8))
                       : *(const bv8*)(sAg  + swz8(lr, (ks-4)*32 + lh*8));
      acc[0] = MFMA(n1r[ks],   b, acc[0]);
      acc[1] = MFMA(n1r[8+ks], b, acc[1]);
    }
    #pragma unroll
    for (int mt = 0; mt < 2; ++mt) {
      uint2 p;
      p.x = pk2(silu_f(acc[mt][0]), silu_f(acc[mt][1]));
      p.y = pk2(silu_f(acc[mt][2]), silu_f(acc[mt][3]));
      *(uint2*)(sN1 + swz8(lr, cb0 + mt*16)) = p;   // rows 8-15 garbage, harmless
    }
  }
  __syncthreads();

  // ---- node GEMM2: hh += N2^T @ n1^T + nb2 (fp32 residual in place + bf16 copy) ----
  {
    fv4 acc[2];
    acc[0] = *(const fv4*)(nb2 + cb0);
    acc[1] = *(const fv4*)(nb2 + cb0 + 16);
    fv4 hv[2];
    if (lr < 8) {
      hv[0] = *(const fv4*)(hh + (node0+lr)*HD + cb0);
      hv[1] = *(const fv4*)(hh + (node0+lr)*HD + cb0 + 16);
    }
    #pragma unroll
    for (int ks = 0; ks < 4; ++ks) {
      bv8 b = *(const bv8*)(sN1 + swz8(lr, ks*32 + lh*8));
      acc[0] = MFMA(n2r[ks],   b, acc[0]);
      acc[1] = MFMA(n2r[4+ks], b, acc[1]);
    }
    if (lr < 8) {
      #pragma unroll
      for (int mt = 0; mt < 2; ++mt) {
        int g = (node0+lr)*HD + cb0 + mt*16;
        fv4 v = hv[mt] + acc[mt];
        *(fv4*)(hh + g) = v;
        uint2 p;
        p.x = pk2(v[0], v[1]);
        p.y = pk2(v[2], v[3]);
        *(uint2*)(hhbout + g) = p;
      }
    }
  }
}

extern "C" void kernel_launch(void* const* d_in, const int* in_sizes, int n_in,
                              void* d_out, int out_size, void* d_ws, size_t ws_size,
                              hipStream_t stream)
{
  (void)in_sizes; (void)n_in; (void)out_size; (void)ws_size;
  const float* h   = (const float*)d_in[0];
  const int*   idx = (const int*)d_in[1];
  const float* eiw = (const float*)d_in[2];
  const float* eib = (const float*)d_in[3];
  const float* ew1 = (const float*)d_in[4];
  const float* eb1 = (const float*)d_in[5];
  const float* ew2 = (const float*)d_in[6];
  const float* eb2 = (const float*)d_in[7];
  const float* cw1 = (const float*)d_in[8];
  const float* cb1 = (const float*)d_in[9];
  const float* cw2 = (const float*)d_in[10];
  const float* nw1 = (const float*)d_in[11];
  const float* nb1 = (const float*)d_in[12];
  const float* nw2 = (const float*)d_in[13];
  const float* nb2 = (const float*)d_in[14];
  const float* eow = (const float*)d_in[15];
  const float* eob = (const float*)d_in[16];

  unsigned char* ws = (unsigned char*)d_ws;
  unsigned short* wt   = (unsigned short*)ws;                 // 1,605,632 B
  float*          hh   = (float*)(ws + 1605632);              // 8,388,608 B (in-place)
  unsigned short* hhbA = (unsigned short*)(ws + 9994240);     // 4,194,304 B
  unsigned short* hhbB = (unsigned short*)(ws + 14188544);    // 4,194,304 B
  float*          xA   = (float*)(ws + 18382848);             // 262,144 B
  float*          xB   = (float*)(ws + 18644992);             // 262,144 B

  prep_kernel<<<(NL*WL_STRIDE + 255)/256, 256, 0, stream>>>(ew1, ew2, cw1, nw1, nw2, wt);
  init_kernel<<<NN*HD/256, 256, 0, stream>>>(h, eiw, eib, hh, hhbA, xA);

  unsigned short* hbs = hhbA; unsigned short* hbd = hhbB;
  float* xs = xA; float* xd = xB;
  for (int l = 0; l < NL; ++l) {
    layer_kernel<<<NN/TM, 256, 0, stream>>>(idx, wt + (size_t)l*WL_STRIDE,
        eb1 + l*128, eb2 + l*128, cb1 + l*128, cw2 + l*128,
        nb1 + l*128, nb2 + l*128,
        ew1 + (size_t)l*257*128,
        hh, hbs, hbd, xs, xd);
    unsigned short* ht = hbs; hbs = hbd; hbd = ht;
    float* t = xs; xs = xd; xd = t;
  }
  out_kernel<<<NN*4/256, 256, 0, stream>>>(hh, xs, eow, eob, (float*)d_out);
}